// Round 16
// baseline (1712.074 us; speedup 1.0000x reference)
//
#include <hip/hip_runtime.h>
#include <hip/hip_bf16.h>
#include <math.h>

#define S_ 2048
#define DM_ 2048

// Full-wave (64-lane) sum via DPP row_shr/row_bcast, broadcast via readlane.
__device__ __forceinline__ float wave_reduce_add_f32(float x) {
  float t;
  t = __int_as_float(__builtin_amdgcn_update_dpp(0, __float_as_int(x), 0x111, 0xf, 0xf, true)); x += t;
  t = __int_as_float(__builtin_amdgcn_update_dpp(0, __float_as_int(x), 0x112, 0xf, 0xf, true)); x += t;
  t = __int_as_float(__builtin_amdgcn_update_dpp(0, __float_as_int(x), 0x114, 0xf, 0xf, true)); x += t;
  t = __int_as_float(__builtin_amdgcn_update_dpp(0, __float_as_int(x), 0x118, 0xf, 0xf, true)); x += t;
  t = __int_as_float(__builtin_amdgcn_update_dpp(0, __float_as_int(x), 0x142, 0xa, 0xf, true)); x += t;
  t = __int_as_float(__builtin_amdgcn_update_dpp(0, __float_as_int(x), 0x143, 0xc, 0xf, true)); x += t;
  return __int_as_float(__builtin_amdgcn_readlane(__float_as_int(x), 63));
}

__device__ __forceinline__ float rdlane(float x, int l) {
  return __int_as_float(__builtin_amdgcn_readlane(__float_as_int(x), l));
}

// ---------------------------------------------------------------------------
// K1: fused projections. proj row (stride 256): k(l2)@0 | v@64 | q(l2)@128 |
// a@192. Scalar qw[row] = sum_j q_j (1-a_j) k_j. (unchanged, harness-proven)
// ---------------------------------------------------------------------------
__global__ __launch_bounds__(256) void k_proj(
    const float* __restrict__ x, const float* __restrict__ Wk,
    const float* __restrict__ Wv, const float* __restrict__ Wq,
    const float* __restrict__ Wa, const float* __restrict__ Wab,
    const float* __restrict__ lam, float* __restrict__ proj,
    float* __restrict__ qwArr)
{
  __shared__ __align__(16) float xs[16 * 40];
  __shared__ __align__(16) float ws[32 * 260];
  const int tid = threadIdx.x;
  const int r0  = blockIdx.x * 16;
  const int ct  = tid & 63;
  const int rt  = tid >> 6;
  float acc[4][4];
  #pragma unroll
  for (int r = 0; r < 4; r++) { acc[r][0] = 0.f; acc[r][1] = 0.f; acc[r][2] = 0.f; acc[r][3] = 0.f; }

  const int sg = tid >> 3;
  const int sm = tid & 7;
  const float* wbase[4] = {Wk, Wv, Wq, Wa};

  for (int k0 = 0; k0 < DM_; k0 += 32) {
    if (tid < 128) {
      const int rr = tid >> 3;
      const int ko = (tid & 7) << 2;
      float4 xv = *(const float4*)(x + (size_t)(r0 + rr) * DM_ + k0 + ko);
      *(float4*)(xs + rr * 40 + ko) = xv;
    }
    #pragma unroll
    for (int p = 0; p < 8; p++) {
      const int c = sg + p * 32;
      const float* wb = wbase[p >> 1];
      const int cc = c - (p >> 1) * 64;
      float4 wv = *(const float4*)(wb + (size_t)cc * DM_ + k0 + sm * 4);
      ws[(sm * 4 + 0) * 260 + c] = wv.x;
      ws[(sm * 4 + 1) * 260 + c] = wv.y;
      ws[(sm * 4 + 2) * 260 + c] = wv.z;
      ws[(sm * 4 + 3) * 260 + c] = wv.w;
    }
    __syncthreads();
    #pragma unroll
    for (int kq = 0; kq < 8; kq++) {
      float4 xv[4];
      #pragma unroll
      for (int r = 0; r < 4; r++) xv[r] = *(const float4*)(xs + (rt * 4 + r) * 40 + kq * 4);
      #pragma unroll
      for (int i = 0; i < 4; i++) {
        const int kk = kq * 4 + i;
        float wv0 = ws[kk * 260 + ct];
        float wv1 = ws[kk * 260 + ct + 64];
        float wv2 = ws[kk * 260 + ct + 128];
        float wv3 = ws[kk * 260 + ct + 192];
        #pragma unroll
        for (int r = 0; r < 4; r++) {
          float xr = (i == 0) ? xv[r].x : (i == 1) ? xv[r].y : (i == 2) ? xv[r].z : xv[r].w;
          acc[r][0] = fmaf(xr, wv0, acc[r][0]);
          acc[r][1] = fmaf(xr, wv1, acc[r][1]);
          acc[r][2] = fmaf(xr, wv2, acc[r][2]);
          acc[r][3] = fmaf(xr, wv3, acc[r][3]);
        }
      }
    }
    __syncthreads();
  }
  float lamv = lam[ct];
  float la = logf(1.f / (1.f + expf(-lamv)) + 1e-8f);
  float bv = Wab[ct];
  #pragma unroll
  for (int r = 0; r < 4; r++) {
    float nk = wave_reduce_add_f32(acc[r][0] * acc[r][0]);
    float nq = wave_reduce_add_f32(acc[r][2] * acc[r][2]);
    nk = fmaxf(sqrtf(nk), 1e-12f);
    nq = fmaxf(sqrtf(nq), 1e-12f);
    float pre = acc[r][3] + bv;
    float rr_ = 1.f / (1.f + expf(-pre));
    float al  = expf(8.f * rr_ * la);
    float kn  = acc[r][0] / nk;
    float qn  = acc[r][2] / nq;
    float qw  = wave_reduce_add_f32(qn * (1.f - al) * kn);
    float* pr = proj + (size_t)(r0 + rt * 4 + r) * 256;
    pr[ct]        = kn;
    pr[64 + ct]   = acc[r][1];
    pr[128 + ct]  = qn;
    pr[192 + ct]  = al;
    if (ct == 0) qwArr[r0 + rt * 4 + r] = qw;
  }
}

// ---------------------------------------------------------------------------
// K2: sequential scan, baseline algorithm, 8 waves x 8 H-rows (512 threads,
// 2 waves/SIMD for latency hiding). lane = v-column. Per step: dots (8 rows)
// -> xch write (pred,kh,y partials as float4) -> barrier -> sum 8 entries ->
// d^2 DPP reduce -> sigmoid -> g -> H update. Wave 0 writes the full y row
// (64 floats) = sum of 8 xch y-partials + qw*g. Staging identical to the
// proven baseline path, done by waves 0-3 (wave-uniform branch).
// ---------------------------------------------------------------------------
struct KQA8 { float4 k[2], q[2], a[2]; float v; };

__device__ __forceinline__ void load_kqa8(const float* __restrict__ slot,
                                          int w, int lane, KQA8& s) {
  const float4* s4 = (const float4*)slot;
  const int o = w * 2;
  #pragma unroll
  for (int i = 0; i < 2; i++) {
    s.k[i] = s4[o + i];         // k @ floats 0   (wave-uniform broadcast)
    s.q[i] = s4[32 + o + i];    // q @ floats 128
    s.a[i] = s4[48 + o + i];    // a @ floats 192
  }
  s.v = slot[64 + lane];        // v @ floats 64, per-lane
}

__device__ __forceinline__ void sstep(int t, float qws, float* __restrict__ inv,
    float4* __restrict__ xchp, float* __restrict__ yb, const float* __restrict__ pb,
    float H[8], KQA8& cur, KQA8& nxt, float& pf, int w, int lane, int tid,
    bool stager)
{
  // phase 0: ring write (data for step t+2), global prefetch (step t+4)
  if (stager) {
    inv[(((t + 2) & 3) << 8) + tid] = pf;
    pf = pb[(size_t)min(t + 4, S_ - 1) * 256 + tid];
  }
  // phase A: derive w_=(1-a)k, qa=q*a; three dots over H_old (8 rows)
  float4 w4[2], qa4[2];
  #pragma unroll
  for (int j = 0; j < 2; j++) {
    w4[j].x = (1.f - cur.a[j].x) * cur.k[j].x;  qa4[j].x = cur.q[j].x * cur.a[j].x;
    w4[j].y = (1.f - cur.a[j].y) * cur.k[j].y;  qa4[j].y = cur.q[j].y * cur.a[j].y;
    w4[j].z = (1.f - cur.a[j].z) * cur.k[j].z;  qa4[j].z = cur.q[j].z * cur.a[j].z;
    w4[j].w = (1.f - cur.a[j].w) * cur.k[j].w;  qa4[j].w = cur.q[j].w * cur.a[j].w;
  }
  float pA = 0.f, kA = 0.f, yA = 0.f;
  #pragma unroll
  for (int j = 0; j < 2; j++) {
    pA = fmaf(cur.q[j].x, H[4*j+0], pA); kA = fmaf(cur.k[j].x, H[4*j+0], kA); yA = fmaf(qa4[j].x, H[4*j+0], yA);
    pA = fmaf(cur.q[j].y, H[4*j+1], pA); kA = fmaf(cur.k[j].y, H[4*j+1], kA); yA = fmaf(qa4[j].y, H[4*j+1], yA);
    pA = fmaf(cur.q[j].z, H[4*j+2], pA); kA = fmaf(cur.k[j].z, H[4*j+2], kA); yA = fmaf(qa4[j].z, H[4*j+2], yA);
    pA = fmaf(cur.q[j].w, H[4*j+3], pA); kA = fmaf(cur.k[j].w, H[4*j+3], kA); yA = fmaf(qa4[j].w, H[4*j+3], yA);
  }
  // exchange + lgkm-only barrier
  xchp[(w << 6) + lane] = make_float4(pA, kA, yA, 0.f);
  asm volatile("s_waitcnt lgkmcnt(0)\n\ts_barrier" ::: "memory");
  float4 e0 = xchp[lane],        e1 = xchp[64 + lane],  e2 = xchp[128 + lane], e3 = xchp[192 + lane];
  float4 e4 = xchp[256 + lane],  e5 = xchp[320 + lane], e6 = xchp[384 + lane], e7 = xchp[448 + lane];
  // issue next step's input reads (latency hidden behind tail)
  load_kqa8(inv + (((t + 1) & 3) << 8), w, lane, nxt);
  float pred = ((e0.x + e1.x) + (e2.x + e3.x)) + ((e4.x + e5.x) + (e6.x + e7.x));
  float kh   = ((e0.y + e1.y) + (e2.y + e3.y)) + ((e4.y + e5.y) + (e6.y + e7.y));
  float d = cur.v - pred;
  float e = wave_reduce_add_f32(d * d);
  float sg = __builtin_amdgcn_rcpf(1.f + __builtin_amdgcn_exp2f(e * -1.4426936f));
  float g = sg * (cur.v - kh);
  // y: wave 0 reconstructs full row from partials and writes 64 floats
  if (w == 0) {
    float yfull = ((e0.z + e1.z) + (e2.z + e3.z)) + ((e4.z + e5.z) + (e6.z + e7.z));
    yb[(size_t)t * 64 + lane] = fmaf(qws, g, yfull);
  }
  // H = a*H + w_*g
  #pragma unroll
  for (int j = 0; j < 2; j++) {
    H[4*j+0] = fmaf(cur.a[j].x, H[4*j+0], w4[j].x * g);
    H[4*j+1] = fmaf(cur.a[j].y, H[4*j+1], w4[j].y * g);
    H[4*j+2] = fmaf(cur.a[j].z, H[4*j+2], w4[j].z * g);
    H[4*j+3] = fmaf(cur.a[j].w, H[4*j+3], w4[j].w * g);
  }
}

__global__ __launch_bounds__(512, 1) void k_scan(const float* __restrict__ proj,
    const float* __restrict__ qwArr, float* __restrict__ ypart)
{
  __shared__ __align__(16) float inv[4 * 256];     // 4-slot input ring
  __shared__ __align__(16) float4 xch[2][512];     // ping-pong exchange, 8 waves
  const int b = blockIdx.x, tid = threadIdx.x;
  const int w = tid >> 6, lane = tid & 63;
  const float* pb  = proj + (size_t)b * S_ * 256;
  const float* qwb = qwArr + (size_t)b * S_;
  float* yb = ypart + (size_t)b * S_ * 64;
  float H[8];
  #pragma unroll
  for (int j = 0; j < 8; j++) H[j] = 0.f;
  // init: slots 0,1 in LDS (512 threads cover both); steps 2,3 in registers
  inv[tid] = pb[tid];
  const bool stager = (tid < 256);
  float pfE = 0.f, pfO = 0.f;
  if (stager) {
    pfE = pb[2 * 256 + tid];
    pfO = pb[3 * 256 + tid];
  }
  __syncthreads();
  KQA8 curA, curB;
  load_kqa8(inv, w, lane, curA);   // step-0 inputs
  for (int t0 = 0; t0 < S_; t0 += 64) {
    float qwv = qwb[t0 + lane];    // 64 qw scalars, one per lane
    for (int tt = 0; tt < 64; tt += 2) {
      float qs0 = rdlane(qwv, tt);
      float qs1 = rdlane(qwv, tt + 1);
      sstep(t0 + tt,     qs0, inv, xch[0], yb, pb, H, curA, curB, pfE, w, lane, tid, stager);
      sstep(t0 + tt + 1, qs1, inv, xch[1], yb, pb, H, curB, curA, pfO, w, lane, tid, stager);
    }
  }
}

// ---------------------------------------------------------------------------
// Wo transpose (2048x64 -> 64x2048).
// ---------------------------------------------------------------------------
__global__ __launch_bounds__(256) void k_trans(const float* __restrict__ Wo,
                                               float* __restrict__ WoT) {
  int i = blockIdx.x * 256 + threadIdx.x;
  int d = i >> 11;
  int c = i & 2047;
  WoT[i] = Wo[(size_t)c * 64 + d];
}

// ---------------------------------------------------------------------------
// K3: RMS-norm over 64 (y rows now pre-summed, 64-wide), * norm_w,
// then yn @ Wo^T.
// ---------------------------------------------------------------------------
__global__ __launch_bounds__(256) void k_out(const float* __restrict__ ypart,
    const float* __restrict__ norm_w, const float* __restrict__ WoT,
    float* __restrict__ out)
{
  __shared__ __align__(16) float yn[16 * 64];
  const int tid = threadIdx.x;
  const int r0  = blockIdx.x * 16;
  const int c0  = blockIdx.y * 512;
  {
    const int r = tid >> 4;
    const int d = (tid & 15) * 4;
    const float* yp = ypart + (size_t)(r0 + r) * 64;
    float4 y0 = *(const float4*)(yp + d);
    float yx = y0.x, yy = y0.y, yz = y0.z, yw = y0.w;
    float sq = yx * yx + yy * yy + yz * yz + yw * yw;
    sq += __shfl_xor(sq, 1, 64);
    sq += __shfl_xor(sq, 2, 64);
    sq += __shfl_xor(sq, 4, 64);
    sq += __shfl_xor(sq, 8, 64);
    float rms = rsqrtf(sq * (1.f / 64.f) + 1e-6f);
    float4 nw = *(const float4*)(norm_w + d);
    yn[r * 64 + d + 0] = yx * rms * nw.x;
    yn[r * 64 + d + 1] = yy * rms * nw.y;
    yn[r * 64 + d + 2] = yz * rms * nw.z;
    yn[r * 64 + d + 3] = yw * rms * nw.w;
  }
  __syncthreads();
  const int ctq = tid & 127;
  const int rt  = tid >> 7;
  float acc[8][4];
  #pragma unroll
  for (int r = 0; r < 8; r++) { acc[r][0] = 0.f; acc[r][1] = 0.f; acc[r][2] = 0.f; acc[r][3] = 0.f; }
  #pragma unroll 8
  for (int d = 0; d < 64; d++) {
    float4 wv = *(const float4*)(WoT + (size_t)d * 2048 + c0 + ctq * 4);
    #pragma unroll
    for (int r = 0; r < 8; r++) {
      float yv = yn[(rt * 8 + r) * 64 + d];
      acc[r][0] = fmaf(yv, wv.x, acc[r][0]);
      acc[r][1] = fmaf(yv, wv.y, acc[r][1]);
      acc[r][2] = fmaf(yv, wv.z, acc[r][2]);
      acc[r][3] = fmaf(yv, wv.w, acc[r][3]);
    }
  }
  #pragma unroll
  for (int r = 0; r < 8; r++) {
    float4 o; o.x = acc[r][0]; o.y = acc[r][1]; o.z = acc[r][2]; o.w = acc[r][3];
    *(float4*)(out + (size_t)(r0 + rt * 8 + r) * 2048 + c0 + ctq * 4) = o;
  }
}

extern "C" void kernel_launch(void* const* d_in, const int* in_sizes, int n_in,
                              void* d_out, int out_size, void* d_ws, size_t ws_size,
                              hipStream_t stream) {
  const float* x   = (const float*)d_in[0];
  const float* Wk  = (const float*)d_in[1];
  const float* Wv  = (const float*)d_in[2];
  const float* Wq  = (const float*)d_in[3];
  const float* Wa  = (const float*)d_in[4];
  const float* Wab = (const float*)d_in[5];
  const float* lam = (const float*)d_in[6];
  const float* nw  = (const float*)d_in[7];
  const float* Wo  = (const float*)d_in[8];
  float* out = (float*)d_out;

  float* wsf   = (float*)d_ws;
  float* proj  = wsf;                 // 4*2048*256 = 2,097,152 floats
  float* ypart = wsf + 2097152;       // 4*2048*64  =   524,288 floats
  float* WoT   = wsf + 2621440;       // 64*2048    =   131,072 floats
  float* qwArr = wsf + 2752512;       // 4*2048     =     8,192 floats  (11.04 MB total)

  k_trans<<<dim3(512), dim3(256), 0, stream>>>(Wo, WoT);
  k_proj <<<dim3(512), dim3(256), 0, stream>>>(x, Wk, Wv, Wq, Wa, Wab, lam, proj, qwArr);
  k_scan <<<dim3(4),   dim3(512), 0, stream>>>(proj, qwArr, ypart);
  k_out  <<<dim3(512, 4), dim3(256), 0, stream>>>(ypart, nw, WoT, out);
}